// Round 10
// baseline (201.332 us; speedup 1.0000x reference)
//
#include <hip/hip_runtime.h>
#include <math.h>

#define BB 4
#define NN 2048
#define DD 512
#define HH 8
#define DH 64
#define MM 256
#define BH 32            // B*H
#define CHK 128
#define NCH 16           // N / CHK
#define ROWS (BH*NN)     // 65536

constexpr float NRM   = 0.35355339059327373f;  // 64^-0.25
constexpr float RATIO = 0.0625f;               // 256^-0.5
constexpr float EPSK  = 1e-4f;
constexpr float EPSD  = 1e-6f;
constexpr float REPS  = 0.0625f * 1e-4f;       // RATIO*EPSK

// ---------------- workspace byte offsets ----------------
#define OFFB_QP   ((size_t)0)
#define OFFB_SP   ((size_t)33554432)
#define OFFB_KP   (OFFB_SP + (size_t)16777216)
#define OFFB_VT   (OFFB_KP + (size_t)33554432)
#define OFFB_Z    (OFFB_VT + (size_t)8388608)
#define OFFB_KMP  (OFFB_Z  + (size_t)524288)
#define OFFB_SF   (OFFB_KMP + (size_t)4096)
#define OFFB_PJB  (OFFB_SF + (size_t)4096)

typedef __attribute__((ext_vector_type(8))) short short8;
typedef __attribute__((ext_vector_type(4))) float f32x4;

__device__ __forceinline__ float b2f(ushort u) {
  union { float f; unsigned int i; } x; x.i = ((unsigned int)u) << 16; return x.f;
}
__device__ __forceinline__ ushort f2b(float f) {  // RNE
  unsigned int u = __float_as_uint(f);
  unsigned int r = (u + 0x7FFFu + ((u >> 16) & 1u)) >> 16;
  return (ushort)r;
}

#define MFMA(a,b,c) __builtin_amdgcn_mfma_f32_16x16x32_bf16(a, b, c, 0, 0, 0)

// proj fp32 [256][64] -> bf16 (done once)
__global__ __launch_bounds__(256) void prep_kernel(const float* __restrict__ proj,
                                                   char* __restrict__ ws) {
  const int i = blockIdx.x*256 + threadIdx.x;     // 4096 threads x 4 elems
  float4 v = *(const float4*)(proj + (size_t)i*4);
  ushort4 o;
  o.x = f2b(v.x); o.y = f2b(v.y); o.z = f2b(v.z); o.w = f2b(v.w);
  *(ushort4*)((ushort*)(ws + OFFB_PJB) + (size_t)i*4) = o;
}

// ---------------------------------------------------------------------------
// Merged Q+K feature body. 64 rows/block; proj halves staged ONCE and used by
// both Q and K MFMAs (bf16 single precision, no residual).
// Q: per-row max; qp = RATIO*(exp(dash-diag-rm)+EPSK) -> bf16
// K: block max m_blk -> kmp[blk]; t = exp(dash-diag-m_blk) -> bf16
// LDS: xq[64][72]@0 9216 | xk@9216 9216 | ps[128][72]@18432 18432 (end 36864)
//      epilogue qt[64][264]@0 33792 (overlap) | diag_q@36864 diag_k@37120
//      wmax@37376 (1024) | kred@38400 -> total 38416 B, 4 blocks/CU.
// ---------------------------------------------------------------------------
__device__ __forceinline__ void featqk_body(const float* __restrict__ qin,
                                            const float* __restrict__ kin,
                                            const ushort* __restrict__ projb,
                                            char* __restrict__ ws,
                                            char* lds, int blk) {
  ushort* xq = (ushort*)lds;
  ushort* xk = xq + 64*72;
  ushort* ps = xk + 64*72;                 // [128][72]
  ushort* qt = (ushort*)lds;               // [64][264] (epilogue)
  float* diag_q = (float*)(lds + 36864);
  float* diag_k = (float*)(lds + 37120);
  float (*wmax)[4] = (float(*)[4])(lds + 37376);
  float* kred = (float*)(lds + 38400);

  const int t  = threadIdx.x;
  const int w  = t >> 6;
  const int l  = t & 63;
  const int lq = l >> 4;
  const int ln = l & 15;

  const int rowbase = blk * 64;
  const int bh = rowbase >> 11;
  const int b  = bh >> 3, h = bh & 7;
  const int n0 = rowbase & (NN - 1);

  // ---- stage Xq, Xk (scaled bf16) + diags ----
  {
    const int r  = t >> 2;
    const int c0 = (t & 3) * 16;
    const size_t off = ((size_t)(b*NN + n0 + r))*DD + h*DH + c0;
    const float* srcq = qin + off;
    const float* srck = kin + off;
    float sq = 0.f, sk = 0.f;
    ushort hq[16], hk[16];
    #pragma unroll
    for (int j = 0; j < 4; ++j) {
      float4 vq = *(const float4*)(srcq + j*4);
      float4 vk = *(const float4*)(srck + j*4);
      float aq[4] = {vq.x*NRM, vq.y*NRM, vq.z*NRM, vq.w*NRM};
      float ak[4] = {vk.x*NRM, vk.y*NRM, vk.z*NRM, vk.w*NRM};
      #pragma unroll
      for (int x = 0; x < 4; ++x) {
        sq += aq[x]*aq[x]; sk += ak[x]*ak[x];
        hq[4*j+x] = f2b(aq[x]); hk[4*j+x] = f2b(ak[x]);
      }
    }
    *(short8*)(xq + r*72 + c0)     = *(short8*)&hq[0];
    *(short8*)(xq + r*72 + c0 + 8) = *(short8*)&hq[8];
    *(short8*)(xk + r*72 + c0)     = *(short8*)&hk[0];
    *(short8*)(xk + r*72 + c0 + 8) = *(short8*)&hk[8];
    sq += __shfl_xor(sq, 1); sq += __shfl_xor(sq, 2);
    sk += __shfl_xor(sk, 1); sk += __shfl_xor(sk, 2);
    if ((t & 3) == 0) { diag_q[r] = 0.5f*sq; diag_k[r] = 0.5f*sk; }
  }

  f32x4 accq[4][4], acck[4][4];
  #pragma unroll
  for (int mt = 0; mt < 4; ++mt)
    #pragma unroll
    for (int c = 0; c < 4; ++c) {
      accq[mt][c] = (f32x4){0.f,0.f,0.f,0.f};
      acck[mt][c] = (f32x4){0.f,0.f,0.f,0.f};
    }

  // ---- two proj halves, staged once, shared by Q and K MFMAs ----
  #pragma unroll
  for (int p = 0; p < 2; ++p) {
    if (p) __syncthreads();
    #pragma unroll
    for (int ld = 0; ld < 4; ++ld) {
      int flat = t + 256*ld;              // < 1024 : 128 rows x 8 granules
      int r = flat >> 3, g = flat & 7;
      *(short8*)(ps + r*72 + g*8) = *(const short8*)(projb + (size_t)(p*128 + r)*DH + g*8);
    }
    __syncthreads();
    #pragma unroll
    for (int kk = 0; kk < 2; ++kk) {
      short8 aq[4], ak[4];
      #pragma unroll
      for (int mt = 0; mt < 4; ++mt) {
        aq[mt] = *(const short8*)(xq + (mt*16 + ln)*72 + kk*32 + lq*8);
        ak[mt] = *(const short8*)(xk + (mt*16 + ln)*72 + kk*32 + lq*8);
      }
      #pragma unroll
      for (int ntl = 0; ntl < 2; ++ntl) {
        short8 bf = *(const short8*)(ps + (w*32 + ntl*16 + ln)*72 + kk*32 + lq*8);
        #pragma unroll
        for (int mt = 0; mt < 4; ++mt) {
          accq[mt][2*p+ntl] = MFMA(aq[mt], bf, accq[mt][2*p+ntl]);
          acck[mt][2*p+ntl] = MFMA(ak[mt], bf, acck[mt][2*p+ntl]);
        }
      }
    }
  }

  // ---- per-wave reductions: Q row-max partials, K wave max ----
  #pragma unroll
  for (int mt = 0; mt < 4; ++mt)
    #pragma unroll
    for (int reg = 0; reg < 4; ++reg) {
      float m = accq[mt][0][reg];
      #pragma unroll
      for (int c = 1; c < 4; ++c) m = fmaxf(m, accq[mt][c][reg]);
      m = fmaxf(m, __shfl_xor(m, 1));
      m = fmaxf(m, __shfl_xor(m, 2));
      m = fmaxf(m, __shfl_xor(m, 4));
      m = fmaxf(m, __shfl_xor(m, 8));
      if (ln == 0) wmax[mt*16 + lq*4 + reg][w] = m;
    }
  {
    float mx = -1e30f;
    #pragma unroll
    for (int mt = 0; mt < 4; ++mt)
      #pragma unroll
      for (int c = 0; c < 4; ++c)
        #pragma unroll
        for (int reg = 0; reg < 4; ++reg) mx = fmaxf(mx, acck[mt][c][reg]);
    #pragma unroll
    for (int m = 1; m < 64; m <<= 1) mx = fmaxf(mx, __shfl_xor(mx, m));
    if (l == 0) kred[w] = mx;
  }
  __syncthreads();   // wmax/kred ready; all ps/xq/xk reads done -> qt free

  const float km = fmaxf(fmaxf(kred[0], kred[1]), fmaxf(kred[2], kred[3]));
  if (t == 0) ((float*)(ws + OFFB_KMP))[blk] = km;

  // ---- Q epilogue ----
  #pragma unroll
  for (int mt = 0; mt < 4; ++mt)
    #pragma unroll
    for (int reg = 0; reg < 4; ++reg) {
      const int row = mt*16 + lq*4 + reg;
      float4 wm4 = *(const float4*)&wmax[row][0];
      const float rm = fmaxf(fmaxf(wm4.x, wm4.y), fmaxf(wm4.z, wm4.w));
      const float dg = diag_q[row];
      #pragma unroll
      for (int c = 0; c < 4; ++c) {
        const int f = (c >> 1)*128 + w*32 + (c & 1)*16 + ln;
        qt[row*264 + f] = f2b(RATIO*(__expf(accq[mt][c][reg] - dg - rm) + EPSK));
      }
    }
  __syncthreads();
  {
    ushort* dstbase = (ushort*)(ws + OFFB_QP) + (size_t)rowbase*MM;
    #pragma unroll
    for (int ld = 0; ld < 8; ++ld) {
      int flat = t + 256*ld;
      int row = flat >> 5, g = flat & 31;
      *(short8*)(dstbase + (size_t)row*MM + g*8) = *(const short8*)(qt + row*264 + g*8);
    }
  }
  __syncthreads();   // qt reads done -> safe for K epilogue

  // ---- K epilogue ----
  #pragma unroll
  for (int mt = 0; mt < 4; ++mt)
    #pragma unroll
    for (int reg = 0; reg < 4; ++reg) {
      const int row = mt*16 + lq*4 + reg;
      const float dg = diag_k[row];
      #pragma unroll
      for (int c = 0; c < 4; ++c) {
        const int f = (c >> 1)*128 + w*32 + (c & 1)*16 + ln;
        qt[row*264 + f] = f2b(__expf(acck[mt][c][reg] - dg - km));
      }
    }
  __syncthreads();
  {
    ushort* dstbase = (ushort*)(ws + OFFB_KP) + (size_t)rowbase*MM;
    #pragma unroll
    for (int ld = 0; ld < 8; ++ld) {
      int flat = t + 256*ld;
      int row = flat >> 5, g = flat & 31;
      *(short8*)(dstbase + (size_t)row*MM + g*8) = *(const short8*)(qt + row*264 + g*8);
    }
  }
}

// Vt[bh][e][n] = bf16(V[b][n][h*64+e])
__device__ __forceinline__ void vt_body(const float* __restrict__ value,
                                        char* __restrict__ ws,
                                        char* lds, int blk) {
  float (*vsh)[68] = (float(*)[68])lds;   // [128][68]
  const int t = threadIdx.x;
  const int bh = blk >> 4, nc = blk & 15;
  const int b = bh >> 3, h = bh & 7;
  const int n0 = nc * CHK;
  #pragma unroll
  for (int l = 0; l < 8; ++l) {
    int flat = t + 256*l;
    int r = flat >> 4, g = flat & 15;
    *(float4*)&vsh[r][g*4] = *(const float4*)(value + ((size_t)(b*NN + n0 + r))*DD + h*DH + g*4);
  }
  __syncthreads();
  const int e = t & 63, qd = t >> 6;
  ushort* vt = (ushort*)(ws + OFFB_VT) + ((size_t)bh*DH + e)*NN + n0 + qd*32;
  #pragma unroll
  for (int p = 0; p < 16; ++p) {
    unsigned int lo = f2b(vsh[qd*32 + 2*p][e]);
    unsigned int hi = f2b(vsh[qd*32 + 2*p + 1][e]);
    ((unsigned int*)vt)[p] = lo | (hi << 16);
  }
}

// mega: blocks [0,1024) merged Q+K features; [1024,1536) V-transpose
__global__ __launch_bounds__(256) void mega_kernel(const float* __restrict__ q,
                                                   const float* __restrict__ k,
                                                   const float* __restrict__ v,
                                                   char* __restrict__ ws) {
  __shared__ __align__(16) char lds[38416];
  const ushort* projb = (const ushort*)(ws + OFFB_PJB);
  const int blk = blockIdx.x;
  if (blk < 1024) featqk_body(q, k, projb, ws, lds, blk);
  else            vt_body(v, ws, lds, blk - 1024);
}

// sfac[blk] = RATIO * exp(m_blk - km[bh])
__global__ __launch_bounds__(256) void sfac_kernel(char* __restrict__ ws) {
  const int blk = blockIdx.x*256 + threadIdx.x;   // < 1024
  const int bh = blk >> 5;
  const float* kmp = (const float*)(ws + OFFB_KMP);
  float km = -1e30f;
  #pragma unroll
  for (int i = 0; i < 32; ++i) km = fmaxf(km, kmp[bh*32 + i]);
  ((float*)(ws + OFFB_SF))[blk] = RATIO * __expf(kmp[blk] - km);
}

// ---------------------------------------------------------------------------
// MFMA chunk-scan, 512 blocks (bh x 16-feature slice). kp rescale (t -> kp)
// applied during kpT staging: kp = fmaf(t, sfac_row, REPS).
// ---------------------------------------------------------------------------
__global__ __launch_bounds__(256) void sprefix_kernel(char* __restrict__ ws) {
  __shared__ __align__(16) unsigned int kpTu[16*68];   // [m 16][seq-pair 64 +pad]
  __shared__ __align__(16) ushort Vts[64*136];         // [e 64][seq 128 +pad]
  __shared__ float zred[16][16];

  const int t  = threadIdx.x;
  const int w  = t >> 6;
  const int l  = t & 63;
  const int lq = l >> 4;
  const int ln = l & 15;
  const int bh = blockIdx.x >> 4;
  const int ms = blockIdx.x & 15;       // feature slice [ms*16, ms*16+16)

  const ushort* kpb = (const ushort*)(ws + OFFB_KP) + (size_t)bh*NN*MM + ms*16;
  const ushort* vtb = (const ushort*)(ws + OFFB_VT) + (size_t)bh*DH*NN;
  const float*  sf  = (const float*)(ws + OFFB_SF);
  ushort* spb = (ushort*)(ws + OFFB_SP) + (size_t)bh*NCH*DH*MM + ms*16;
  float*  zb  = (float*)(ws + OFFB_Z) + (size_t)bh*NCH*MM + ms*16;

  f32x4 acc = (f32x4){0.f,0.f,0.f,0.f};
  float zrun = 0.f;

  for (int tc = 0; tc < NCH; ++tc) {
    __syncthreads();

    if (t < 16) {
      if (tc > 0) {
        float s = 0.f;
        #pragma unroll
        for (int q = 0; q < 16; ++q) s += zred[q][t];
        zrun += s;
      }
      zb[(size_t)tc*MM + t] = zrun;
    }
    // dump exclusive S prefix (C-layout: row=e, col=m)
    {
      ushort* sp = spb + (size_t)tc*DH*MM;
      #pragma unroll
      for (int reg = 0; reg < 4; ++reg)
        sp[(size_t)(w*16 + lq*4 + reg)*MM + ln] = f2b(acc[reg]);
    }

    // stage kpT with rescale: kpTu[m][jp] = kp[2jp][m] | kp[2jp+1][m]<<16
    const ushort* kslice = kpb + (size_t)tc*CHK*MM;
    if (t < 128) {
      int jp = t >> 1, mo = t & 1;
      float s0 = sf[bh*32 + tc*2 + (jp >> 5)];
      short8 a = *(const short8*)(kslice + (size_t)(2*jp)*MM + mo*8);
      short8 c = *(const short8*)(kslice + (size_t)(2*jp+1)*MM + mo*8);
      #pragma unroll
      for (int i = 0; i < 8; ++i) {
        ushort ua = f2b(fmaf(b2f((ushort)a[i]), s0, REPS));
        ushort uc = f2b(fmaf(b2f((ushort)c[i]), s0, REPS));
        kpTu[(mo*8 + i)*68 + jp] = (unsigned int)ua | ((unsigned int)uc << 16);
      }
    }
    // stage Vt chunk [64 e][128 seq]
    #pragma unroll
    for (int it = 0; it < 4; ++it) {
      int slot = t + 256*it;           // < 1024
      int e = slot >> 4, g = slot & 15;
      *(short8*)(Vts + e*136 + g*8) = *(const short8*)(vtb + (size_t)e*NN + tc*CHK + g*8);
    }
    __syncthreads();

    // z partials (consumed at next loop top)
    {
      int m = t & 15, q = t >> 4;
      float s = 0.f;
      #pragma unroll
      for (int u = 0; u < 4; ++u) {
        unsigned int p = kpTu[m*68 + q*4 + u];
        s += b2f((ushort)(p & 0xFFFF)) + b2f((ushort)(p >> 16));
      }
      zred[q][m] = s;
    }

    // MFMA: D[e][m] += sum_k Vt[e][k] * kpT[m][k]; wave w owns e-tile w
    #pragma unroll
    for (int kk = 0; kk < 4; ++kk) {
      short8 af = *(const short8*)(Vts + (w*16 + ln)*136 + kk*32 + lq*8);
      short8 bf = *(const short8*)((const ushort*)kpTu + (size_t)ln*136 + kk*32 + lq*8);
      acc = MFMA(af, bf, acc);
    }
  }
}

// ---------------------------------------------------------------------------
// Fused per-chunk kernel: merged K-loop does BOTH Sc = Qp Kp^T (balanced
// lower-tri tiles, wave w owns row-tiles {w, 7-w}) AND oacc += Qp @ S_prev,
// sharing one qp staging. Then mask/rowsum/P, den, P@V, epilogue.
// NOTE: __syncthreads() after the den block is REQUIRED (R8 race).
// ---------------------------------------------------------------------------
__global__ __launch_bounds__(256) void fused_kernel(float* __restrict__ out,
                                                    char* __restrict__ ws) {
  __shared__ __align__(16) char lds[52224];
  __shared__ float den_i[128];
  __shared__ float dinv_s[128];

  const int t  = threadIdx.x;
  const int w  = t >> 6;
  const int l  = t & 63;
  const int lq = l >> 4;
  const int ln = l & 15;
  const int rt0 = w;          // row-tile A
  const int rt1 = 7 - w;      // row-tile B  (rt0 < rt1)
  const int blk = blockIdx.x;
  const int bh = blk >> 4, tc = blk & 15;
  const int b = bh >> 3, h = bh & 7;
  const size_t rowbase = (size_t)bh*NN + tc*CHK;

  const ushort* qpg = (const ushort*)(ws + OFFB_QP) + rowbase*MM;
  const ushort* kpg = (const ushort*)(ws + OFFB_KP) + rowbase*MM;
  const ushort* spg = (const ushort*)(ws + OFFB_SP) + (size_t)blk*DH*MM;
  const float*  sf  = (const float*)(ws + OFFB_SF);
  const float sc0 = sf[blk*2], sc1 = sf[blk*2 + 1];

  ushort* qs = (ushort*)lds;            // [128][72]
  ushort* ks = qs + 128*72;             // [128][72]
  ushort* ss = ks + 128*72;             // [64][72]

  f32x4 acc[2][8];
  #pragma unroll
  for (int mt = 0; mt < 2; ++mt)
    #pragma unroll
    for (int nt = 0; nt < 8; ++nt) acc[mt][nt] = (f32x4){0.f,0.f,0.f,0.f};
  f32x4 oacc[2][4];
  #pragma unroll
  for (int mt = 0; mt < 2; ++mt)
    #pragma unroll
    for (int nt = 0; nt < 4; ++nt) oacc[mt][nt] = (f32x4){0.f,0.f,0.f,0.f};

  // ---- merged K-loop: Sc (Qp Kp^T) + oacc (Qp S_prev), K=256 in 4x64 ----
  for (int mc = 0; mc < 4; ++mc) {
    __syncthreads();
    #pragma unroll
    for (int ld2 = 0; ld2 < 4; ++ld2) {
      int flat = t + 256*ld2; int r = flat >> 3, g = flat & 7;
      *(short8*)(qs + r*72 + g*8) = *(const short8*)(qpg + (size_t)r*MM + mc*64 + g*8);
    }
    #pragma unroll
    for (int ld2 = 0; ld2 < 4; ++ld2) {
      int flat = t + 256*ld2; int r = flat >> 3, g = flat & 7;
      short8 kv = *(const short8*)(kpg + (size_t)r*MM + mc*64 + g*8);
      const float sc = (r & 64) ? sc1 : sc0;
      ushort ov[8];
      #pragma unroll
      for (int i = 0; i < 8; ++i) ov[i] = f2b(fmaf(b2f((ushort)kv[i]), sc, REPS));
      *(short8*)(ks + r*72 + g*8) = *(short8*)&ov[0];
    }
    #pragma unroll
    for (int ld2 = 0; ld2 < 2; ++ld2) {
      int flat = t + 256*ld2; int e = flat >> 3, g = flat & 7;
      *(short8*)(ss + e*72 + g*8) = *(const short8*)(spg + (size_t)e*MM + mc*64 + g*8);
    }
    __syncthreads();
    #pragma unroll
    for (int kk = 0; kk < 2; ++kk) {
      short8 af0 = *(const short8*)(qs + (rt0*16 + ln)*72 + kk*32 + lq*8);
      short8 af1 = *(const short8*)(qs + (rt1*16 + ln)*72 + kk*32 + lq*8);
      #pragma unroll
      for (int nt = 0; nt < 8; ++nt) {
        if (nt <= rt1) {
          short8 bf = *(const short8*)(ks + (nt*16 + ln)*72 + kk*32 + lq*8);
          if (nt <= rt0) acc[0][nt] = MFMA(af0, bf, acc[0][nt]);
          acc[1][nt] = MFMA(af1, bf, acc[1][nt]);
        }
      }
      #pragma unroll
      for (int nt = 0; nt < 4; ++nt) {
        short8 bf = *(const short8*)(ss + (nt*16 + ln)*72 + kk*32 + lq*8);
        oacc[0][nt] = MFMA(af0, bf, oacc[0][nt]);
        oacc[1][nt] = MFMA(af1, bf, oacc[1][nt]);
      }
    }
  }

  __syncthreads();   // qs/ks/ss dead -> P + Vts region

  ushort* P   = (ushort*)lds;             // [128][136]
  ushort* Vts = (ushort*)(lds + 34816);   // [64][136]

  float rs[2][4] = {{0,0,0,0},{0,0,0,0}};
  #pragma unroll
  for (int mt = 0; mt < 2; ++mt) {
    const int ibase = (mt ? rt1 : rt0) * 16;
    #pragma unroll
    for (int nt = 0; nt < 8; ++nt)
      #pragma unroll
      for (int reg = 0; reg < 4; ++reg) {
        int i = ibase + lq*4 + reg;
        int j = nt*16 + ln;
        float v = (j <= i) ? acc[mt][nt][reg] : 0.f;
        rs[mt][reg] += v;
        P[i*136 + j] = f2b(v);
      }
  }
  #pragma unroll
  for (int mt = 0; mt < 2; ++mt) {
    const int ibase = (mt ? rt1 : rt0) * 16;
    #pragma unroll
    for (int reg = 0; reg < 4; ++reg) {
      float s = rs[mt][reg];
      s += __shfl_xor(s, 1); s += __shfl_xor(s, 2);
      s += __shfl_xor(s, 4); s += __shfl_xor(s, 8);
      if (ln == 0) den_i[ibase + lq*4 + reg] = s;
    }
  }

  const ushort* vtg = (const ushort*)(ws + OFFB_VT) + (size_t)bh*DH*NN + tc*CHK;
  #pragma unroll
  for (int ld2 = 0; ld2 < 4; ++ld2) {
    int flat = t + 256*ld2; int e = flat >> 4, g = flat & 15;
    *(short8*)(Vts + e*136 + g*8) = *(const short8*)(vtg + (size_t)e*NN + g*8);
  }
  __syncthreads();

  {
    const float* zp = (const float*)(ws + OFFB_Z) + (size_t)blk*MM;
    const int r = t >> 1, hf = t & 1;
    const ushort* qrow = qpg + (size_t)r*MM + hf*128;
    float s = 0.f;
    #pragma unroll
    for (int g = 0; g < 16; ++g) {
      short8 qv = *(const short8*)(qrow + g*8);
      const float* zz = zp + hf*128 + g*8;
      #pragma unroll
      for (int x = 0; x < 8; ++x)
        s += b2f((ushort)qv[x]) * (zz[x] + EPSD);
    }
    s += __shfl_xor(s, 1);
    if (hf == 0) dinv_s[r] = 1.0f / (s + den_i[r]);
  }
  __syncthreads();   // dinv_s visible to all waves before the epilogue

  // ---- oacc += P @ V  (K=128) ----
  #pragma unroll
  for (int kk = 0; kk < 4; ++kk) {
    short8 af0 = *(const short8*)(P + (rt0*16 + ln)*136 + kk*32 + lq*8);
    short8 af1 = *(const short8*)(P + (rt1*16 + ln)*136 + kk*32 + lq*8);
    #pragma unroll
    for (int nt = 0; nt < 4; ++nt) {
      short8 bf = *(const short8*)(Vts + (nt*16 + ln)*136 + kk*32 + lq*8);
      oacc[0][nt] = MFMA(af0, bf, oacc[0][nt]);
      oacc[1][nt] = MFMA(af1, bf, oacc[1][nt]);
    }
  }

  #pragma unroll
  for (int mt = 0; mt < 2; ++mt) {
    const int ibase = (mt ? rt1 : rt0) * 16;
    #pragma unroll
    for (int reg = 0; reg < 4; ++reg) {
      const int i = ibase + lq*4 + reg;
      const float di = dinv_s[i];
      float* dst = out + ((size_t)(b*NN) + tc*CHK + i)*DD + h*DH;
      #pragma unroll
      for (int nt = 0; nt < 4; ++nt)
        dst[nt*16 + ln] = oacc[mt][nt][reg] * di;
    }
  }
}

extern "C" void kernel_launch(void* const* d_in, const int* in_sizes, int n_in,
                              void* d_out, int out_size, void* d_ws, size_t ws_size,
                              hipStream_t stream) {
  (void)in_sizes; (void)n_in; (void)out_size; (void)ws_size;
  const float* q    = (const float*)d_in[0];
  const float* k    = (const float*)d_in[1];
  const float* v    = (const float*)d_in[2];
  const float* proj = (const float*)d_in[3];
  float* out = (float*)d_out;
  char*  ws  = (char*)d_ws;

  prep_kernel<<<16, 256, 0, stream>>>(proj, ws);
  mega_kernel<<<1536, 256, 0, stream>>>(q, k, v, ws);
  sfac_kernel<<<4, 256, 0, stream>>>(ws);
  sprefix_kernel<<<512, 256, 0, stream>>>(ws);
  fused_kernel<<<512, 256, 0, stream>>>(out, ws);
}